// Round 4
// baseline (1186.363 us; speedup 1.0000x reference)
//
#include <hip/hip_runtime.h>
#include <stdint.h>
#include <math.h>

#define B_ 32
#define T_ 512
#define D_ 1024
#define H_ 2048
#define V_ 50257
#define S_ 16
#define M_ (B_*T_)
#define TW_ 511

typedef __attribute__((ext_vector_type(8))) short bf16x8;
typedef __attribute__((ext_vector_type(4))) float f32x4;
typedef __attribute__((ext_vector_type(8))) unsigned short us8;
typedef __attribute__((ext_vector_type(4))) unsigned short us4;

__device__ inline unsigned short f2bf(float f) {
  uint32_t u = __builtin_bit_cast(uint32_t, f);
  uint32_t r = (u + 0x7FFFu + ((u >> 16) & 1u)) >> 16;
  return (unsigned short)r;
}
__device__ inline float bf2f(unsigned short h) {
  uint32_t u = ((uint32_t)h) << 16;
  return __builtin_bit_cast(float, u);
}

__device__ inline f32x4 mfma_bf16(bf16x8 a, bf16x8 b, f32x4 c) {
  return __builtin_amdgcn_mfma_f32_16x16x32_bf16(a, b, c, 0, 0, 0);
}

// async 16B global->LDS; LDS dest = wave-uniform base + lane*16
__device__ inline void gl2lds(const unsigned short* g, unsigned short* l) {
  __builtin_amdgcn_global_load_lds(
      (const __attribute__((address_space(1))) unsigned int*)g,
      (__attribute__((address_space(3))) unsigned int*)l,
      16, 0, 0);
}

// ---------------- prep: gu[d]=ln_g[d]*mean_s(wg_w[d,s]); scal: [0]=sum(gu),
// [1]=dot(ln_b,u)+mean(wg_b), [2]=b2.gu, [3]=sum(b2)
__global__ __launch_bounds__(256) void k_prep(
    const float* __restrict__ wg_w, const float* __restrict__ wg_b,
    const float* __restrict__ ln_g, const float* __restrict__ ln_b,
    const float* __restrict__ b2,
    float* __restrict__ gu, float* __restrict__ scal) {
  __shared__ float r1[4], r2[4], r3[4], r4[4];
  int tid = threadIdx.x;
  float psgu = 0.f, plbu = 0.f, pb2g = 0.f, pb2s = 0.f;
  for (int d = tid; d < D_; d += 256) {
    float s = 0.f;
    #pragma unroll
    for (int j = 0; j < S_; j++) s += wg_w[d*S_ + j];
    float uu = s * (1.0f/S_);
    float g = ln_g[d] * uu;
    gu[d] = g;
    psgu += g;
    plbu += ln_b[d] * uu;
    pb2g += b2[d] * g;
    pb2s += b2[d];
  }
  for (int off = 32; off > 0; off >>= 1) {
    psgu += __shfl_down(psgu, off, 64); plbu += __shfl_down(plbu, off, 64);
    pb2g += __shfl_down(pb2g, off, 64); pb2s += __shfl_down(pb2s, off, 64);
  }
  if ((tid & 63) == 0) { int w = tid>>6; r1[w]=psgu; r2[w]=plbu; r3[w]=pb2g; r4[w]=pb2s; }
  __syncthreads();
  if (tid == 0) {
    float sgu = r1[0]+r1[1]+r1[2]+r1[3];
    float lbu = r2[0]+r2[1]+r2[2]+r2[3];
    float ub = 0.f;
    for (int j = 0; j < S_; j++) ub += wg_b[j];
    scal[0] = sgu;
    scal[1] = lbu + ub * (1.0f/S_);
    scal[2] = r3[0]+r3[1]+r3[2]+r3[3];
    scal[3] = r4[0]+r4[1]+r4[2]+r4[3];
  }
}

// ---------------- prep2: w2gu[h] = W2[h,:].gu ; w2s[h] = sum_d W2[h,d]
__global__ __launch_bounds__(256) void k_prep2(
    const float* __restrict__ W2, const float* __restrict__ gu,
    float* __restrict__ w2gu, float* __restrict__ w2s) {
  int h = blockIdx.x*4 + (threadIdx.x >> 6);
  int lane = threadIdx.x & 63;
  const float4* row = (const float4*)(W2 + (size_t)h*D_);
  const float4* g4 = (const float4*)gu;
  float sg = 0.f, ss = 0.f;
  #pragma unroll
  for (int k = 0; k < 4; k++) {
    float4 w = row[lane + k*64];
    float4 g = g4[lane + k*64];
    sg += w.x*g.x + w.y*g.y + w.z*g.z + w.w*g.w;
    ss += w.x + w.y + w.z + w.w;
  }
  for (int off = 32; off > 0; off >>= 1) { sg += __shfl_down(sg, off, 64); ss += __shfl_down(ss, off, 64); }
  if (lane == 0) { w2gu[h] = sg; w2s[h] = ss; }
}

// ---------------- gather embed + hi/lo split + exact per-token e.gu / sum(e)
__global__ __launch_bounds__(256) void k_gsplit(
    const int* __restrict__ seq, const float* __restrict__ embed,
    const float* __restrict__ gu,
    unsigned short* __restrict__ ehi, unsigned short* __restrict__ elo,
    float* __restrict__ es, float* __restrict__ egu) {
  int m = blockIdx.x;
  int tok = seq[m];
  int tid = threadIdx.x;
  int d = tid * 4;
  float4 v = *(const float4*)(embed + (size_t)tok*D_ + d);
  float4 g = *(const float4*)(gu + d);
  unsigned short h0=f2bf(v.x), h1=f2bf(v.y), h2=f2bf(v.z), h3=f2bf(v.w);
  us4 hv = {h0,h1,h2,h3};
  us4 lv = {f2bf(v.x-bf2f(h0)), f2bf(v.y-bf2f(h1)), f2bf(v.z-bf2f(h2)), f2bf(v.w-bf2f(h3))};
  *(us4*)(ehi + (size_t)m*D_ + d) = hv;
  *(us4*)(elo + (size_t)m*D_ + d) = lv;
  float pe = v.x + v.y + v.z + v.w;
  float pg = v.x*g.x + v.y*g.y + v.z*g.z + v.w*g.w;
  __shared__ float le[4], lg[4];
  for (int off = 32; off > 0; off >>= 1) { pe += __shfl_down(pe, off, 64); pg += __shfl_down(pg, off, 64); }
  if ((tid & 63) == 0) { le[tid>>6] = pe; lg[tid>>6] = pg; }
  __syncthreads();
  if (tid == 0) {
    es[m]  = le[0]+le[1]+le[2]+le[3];
    egu[m] = lg[0]+lg[1]+lg[2]+lg[3];
  }
}

// ---------------- transpose + hi/lo split:  W (K x N) -> Thi/Tlo (N x K) bf16
__global__ __launch_bounds__(256) void k_tsplit(
    const float* __restrict__ W, unsigned short* __restrict__ Thi,
    unsigned short* __restrict__ Tlo, int K, int N) {
  __shared__ float tile[32][33];
  int k0 = blockIdx.x * 32, n0 = blockIdx.y * 32;
  int tx = threadIdx.x & 31, ty = threadIdx.x >> 5;
  for (int i = ty; i < 32; i += 8)
    tile[i][tx] = W[(size_t)(k0+i)*N + n0 + tx];
  __syncthreads();
  for (int i = ty; i < 32; i += 8) {
    float v = tile[tx][i];
    unsigned short hi = f2bf(v);
    size_t o = (size_t)(n0+i)*K + k0 + tx;
    Thi[o] = hi;
    if (Tlo) Tlo[o] = f2bf(v - bf2f(hi));
  }
}

// ---------------- GEMM1: r = relu(e @ w1t + b1) -> rhi (bf16), 3-pass split.
// Epilogue also accumulates exact projections rg[m]=sum_h r*w2gu[h], rsum[m]=sum_h r*w2s[h].
__global__ __launch_bounds__(256) void k_gemm1(
    const unsigned short* __restrict__ ehi, const unsigned short* __restrict__ elo,
    const unsigned short* __restrict__ Bhi, const unsigned short* __restrict__ Blo,
    const float* __restrict__ b1,
    const float* __restrict__ w2gu, const float* __restrict__ w2s,
    unsigned short* __restrict__ rhi,
    float* __restrict__ rg, float* __restrict__ rsum) {
  __shared__ unsigned short Ah[128*32], Al[128*32], Bh[128*32], Bl[128*32];
  int m0 = blockIdx.x * 128, n0 = blockIdx.y * 128;
  int tid = threadIdx.x;
  int lane = tid & 63, wave = tid >> 6;
  int wm = (wave & 1) * 64, wn = (wave >> 1) * 64;
  int fr = lane & 15, fq = lane >> 4;
  int srow = lane >> 2;
  // stage-side XOR swizzle: LDS slot (R, c) holds global colblock c ^ ((R>>1)&3)
  int scol = ((lane & 3) ^ ((lane >> 3) & 3)) * 8;
  // read-side: global colblock fq of row R lives at slot fq ^ ((fr>>1)&3)
  int csw = (fq ^ ((fr >> 1) & 3)) * 8;

  f32x4 acc[4][4];
  #pragma unroll
  for (int i=0;i<4;i++)
    #pragma unroll
    for (int j=0;j<4;j++) acc[i][j] = (f32x4){0.f,0.f,0.f,0.f};

  const unsigned short *pAh[2], *pAl[2], *pBh[2], *pBl[2];
  unsigned short *lAh[2], *lAl[2], *lBh[2], *lBl[2];
  #pragma unroll
  for (int t = 0; t < 2; t++) {
    int rb = t*64 + wave*16;
    pAh[t] = ehi + (size_t)(m0 + rb + srow)*D_ + scol;
    pAl[t] = elo + (size_t)(m0 + rb + srow)*D_ + scol;
    pBh[t] = Bhi + (size_t)(n0 + rb + srow)*D_ + scol;
    pBl[t] = Blo + (size_t)(n0 + rb + srow)*D_ + scol;
    lAh[t] = &Ah[rb*32]; lAl[t] = &Al[rb*32];
    lBh[t] = &Bh[rb*32]; lBl[t] = &Bl[rb*32];
  }

  for (int k0 = 0; k0 < D_; k0 += 32) {
    #pragma unroll
    for (int t = 0; t < 2; t++) {
      gl2lds(pAh[t], lAh[t]); gl2lds(pAl[t], lAl[t]);
      gl2lds(pBh[t], lBh[t]); gl2lds(pBl[t], lBl[t]);
      pAh[t] += 32; pAl[t] += 32; pBh[t] += 32; pBl[t] += 32;
    }
    __syncthreads();

    bf16x8 ah[4], al[4], bh[4], bl[4];
    #pragma unroll
    for (int i=0;i<4;i++) {
      ah[i] = *(const bf16x8*)&Ah[(wm + i*16 + fr)*32 + csw];
      al[i] = *(const bf16x8*)&Al[(wm + i*16 + fr)*32 + csw];
      bh[i] = *(const bf16x8*)&Bh[(wn + i*16 + fr)*32 + csw];
      bl[i] = *(const bf16x8*)&Bl[(wn + i*16 + fr)*32 + csw];
    }
    #pragma unroll
    for (int i=0;i<4;i++)
      #pragma unroll
      for (int j=0;j<4;j++) {
        acc[i][j] = mfma_bf16(ah[i], bh[j], acc[i][j]);
        acc[i][j] = mfma_bf16(ah[i], bl[j], acc[i][j]);
        acc[i][j] = mfma_bf16(al[i], bh[j], acc[i][j]);
      }
    __syncthreads();
  }

  // epilogue: relu + bf16 store + exact fp32 projections (reduced over fr lanes)
  float biasj[4], wgj[4], wsj[4];
  int gcj[4];
  #pragma unroll
  for (int j=0;j<4;j++) {
    gcj[j] = n0 + wn + j*16 + fr;
    biasj[j] = b1[gcj[j]];
    wgj[j] = w2gu[gcj[j]];
    wsj[j] = w2s[gcj[j]];
  }
  #pragma unroll
  for (int i=0;i<4;i++) {
    #pragma unroll
    for (int r=0;r<4;r++) {
      int gr = m0 + wm + i*16 + fq*4 + r;
      float sg = 0.f, ss = 0.f;
      #pragma unroll
      for (int j=0;j<4;j++) {
        float v = acc[i][j][r] + biasj[j];
        v = fmaxf(v, 0.f);
        rhi[(size_t)gr*H_ + gcj[j]] = f2bf(v);
        sg += v * wgj[j];
        ss += v * wsj[j];
      }
      #pragma unroll
      for (int off = 8; off > 0; off >>= 1) {
        sg += __shfl_down(sg, off, 16);
        ss += __shfl_down(ss, off, 16);
      }
      if (fr == 0) {
        atomicAdd(&rg[gr], sg);
        atomicAdd(&rsum[gr], ss);
      }
    }
  }
}

// ---------------- GEMM2 (1-pass bf16): x = rhi @ w2t + b2 + gather(embed,seq)
__global__ __launch_bounds__(256) void k_gemm2(
    const unsigned short* __restrict__ Ahi, const unsigned short* __restrict__ Bhig,
    const float* __restrict__ b2, const int* __restrict__ seq,
    const float* __restrict__ embed, float* __restrict__ xout) {
  __shared__ unsigned short Ah[128*32], Bh[128*32];
  int m0 = blockIdx.x * 128, n0 = blockIdx.y * 128;
  int tid = threadIdx.x;
  int lane = tid & 63, wave = tid >> 6;
  int wm = (wave & 1) * 64, wn = (wave >> 1) * 64;
  int fr = lane & 15, fq = lane >> 4;
  int srow = lane >> 2;
  int scol = ((lane & 3) ^ ((lane >> 3) & 3)) * 8;
  int csw = (fq ^ ((fr >> 1) & 3)) * 8;

  f32x4 acc[4][4];
  #pragma unroll
  for (int i=0;i<4;i++)
    #pragma unroll
    for (int j=0;j<4;j++) acc[i][j] = (f32x4){0.f,0.f,0.f,0.f};

  const unsigned short *pA[2], *pB[2];
  unsigned short *lA[2], *lB[2];
  #pragma unroll
  for (int t = 0; t < 2; t++) {
    int rb = t*64 + wave*16;
    pA[t] = Ahi  + (size_t)(m0 + rb + srow)*H_ + scol;
    pB[t] = Bhig + (size_t)(n0 + rb + srow)*H_ + scol;
    lA[t] = &Ah[rb*32]; lB[t] = &Bh[rb*32];
  }

  for (int k0 = 0; k0 < H_; k0 += 32) {
    #pragma unroll
    for (int t = 0; t < 2; t++) {
      gl2lds(pA[t], lA[t]); gl2lds(pB[t], lB[t]);
      pA[t] += 32; pB[t] += 32;
    }
    __syncthreads();

    bf16x8 ah[4], bh[4];
    #pragma unroll
    for (int i=0;i<4;i++) {
      ah[i] = *(const bf16x8*)&Ah[(wm + i*16 + fr)*32 + csw];
      bh[i] = *(const bf16x8*)&Bh[(wn + i*16 + fr)*32 + csw];
    }
    #pragma unroll
    for (int i=0;i<4;i++)
      #pragma unroll
      for (int j=0;j<4;j++)
        acc[i][j] = mfma_bf16(ah[i], bh[j], acc[i][j]);
    __syncthreads();
  }

  #pragma unroll
  for (int j=0;j<4;j++) {
    int gc = n0 + wn + j*16 + fr;
    float bias = b2[gc];
    #pragma unroll
    for (int i=0;i<4;i++) {
      #pragma unroll
      for (int r=0;r<4;r++) {
        int gr = m0 + wm + i*16 + fq*4 + r;
        float h = embed[(size_t)seq[gr]*D_ + gc];
        xout[(size_t)gr*D_ + gc] = acc[i][j][r] + bias + h;
      }
    }
  }
}

// ---------------- per-token stats: sum(x^2) from x; mu/sg from exact projections
__global__ __launch_bounds__(256) void k_stats(
    const float* __restrict__ x, const float* __restrict__ scal,
    const float* __restrict__ es, const float* __restrict__ egu,
    const float* __restrict__ rg, const float* __restrict__ rsum,
    float* __restrict__ meanv, float* __restrict__ rstdv, float* __restrict__ slotv) {
  int m = blockIdx.x, tid = threadIdx.x;
  const float4* xr = (const float4*)(x + (size_t)m*D_);
  float4 v = xr[tid];
  float sq = v.x*v.x + v.y*v.y + v.z*v.z + v.w*v.w;
  __shared__ float lq[4];
  for (int off = 32; off > 0; off >>= 1) sq += __shfl_down(sq, off, 64);
  if ((tid & 63) == 0) lq[tid>>6] = sq;
  __syncthreads();
  if (tid == 0) {
    sq = lq[0]+lq[1]+lq[2]+lq[3];
    float mu = (es[m] + rsum[m] + scal[3]) * (1.0f/D_);
    float sg = egu[m] + rg[m] + scal[2];
    float var = sq * (1.0f/D_) - mu*mu;
    float rs = 1.0f / sqrtf(var + 1e-5f);
    meanv[m] = mu; rstdv[m] = rs;
    slotv[m] = rs * (sg - mu * scal[0]) + scal[1];
  }
}

// ---------------- top-k selection, parallel argmax (stable lowest-index ties)
__global__ __launch_bounds__(256) void k_select(const float* __restrict__ slotv, int* __restrict__ sel) {
  __shared__ float v[TW_];
  __shared__ float bvs[4]; __shared__ int bis[4];
  int b = blockIdx.x, tid = threadIdx.x;
  for (int t = tid; t < TW_; t += 256) v[t] = slotv[(size_t)b*T_ + t];
  __syncthreads();
  for (int k = 0; k < 4; k++) {
    float bv = -3.4e38f; int bi = 0x7fffffff;
    for (int t = tid; t < TW_; t += 256) {
      float x = v[t];
      if (x > bv) { bv = x; bi = t; }
    }
    for (int off = 32; off > 0; off >>= 1) {
      float ov = __shfl_down(bv, off, 64); int oi = __shfl_down(bi, off, 64);
      if (ov > bv || (ov == bv && oi < bi)) { bv = ov; bi = oi; }
    }
    if ((tid & 63) == 0) { bvs[tid>>6] = bv; bis[tid>>6] = bi; }
    __syncthreads();
    if (tid == 0) {
      float fbv = bvs[0]; int fbi = bis[0];
      for (int w = 1; w < 4; w++)
        if (bvs[w] > fbv || (bvs[w] == fbv && bis[w] < fbi)) { fbv = bvs[w]; fbi = bis[w]; }
      sel[b*8 + k] = fbi; v[fbi] = -3.4e38f;
    }
    __syncthreads();
  }
  if (tid == 0) {
    for (int k = 4; k < 6; k++) {          // rev top-2 among first 8, excluding fwd picks
      float best = -3.4e38f; int bi = 0;
      for (int t = 0; t < 8; t++) if (v[t] > best) { best = v[t]; bi = t; }
      sel[b*8 + k] = bi; v[bi] = -3.4e38f;
    }
  }
}

// ---------------- build mem slots (0..5 selected hiddens, 6..15 memory) + query row
__global__ __launch_bounds__(256) void k_buildmem(
    const float* __restrict__ x, const float* __restrict__ meanv, const float* __restrict__ rstdv,
    const float* __restrict__ ln_g, const float* __restrict__ ln_b,
    const float* __restrict__ memory, const int* __restrict__ sel,
    float* __restrict__ mem, float* __restrict__ qv) {
  int s = blockIdx.x, b = blockIdx.y, tid = threadIdx.x;
  int d = tid * 4;
  if (s >= 6 && s < 16) {
    *(float4*)&mem[((size_t)b*S_ + s)*D_ + d] = *(const float4*)&memory[(size_t)s*D_ + d];
    return;
  }
  int t = (s == 16) ? (T_ - 1) : sel[b*8 + s];
  int m = b*T_ + t;
  float mu = meanv[m], rs = rstdv[m];
  float4 xv = *(const float4*)&x[(size_t)m*D_ + d];
  float4 g  = *(const float4*)&ln_g[d];
  float4 lb = *(const float4*)&ln_b[d];
  float4 o;
  o.x = (xv.x - mu)*rs*g.x + lb.x;
  o.y = (xv.y - mu)*rs*g.y + lb.y;
  o.z = (xv.z - mu)*rs*g.z + lb.z;
  o.w = (xv.w - mu)*rs*g.w + lb.w;
  if (s == 16) *(float4*)&qv[(size_t)b*D_ + d] = o;
  else         *(float4*)&mem[((size_t)b*S_ + s)*D_ + d] = o;
}

// ---------------- q = query @ rp_w + rp_b
__global__ __launch_bounds__(256) void k_qproj(
    const float* __restrict__ qv, const float* __restrict__ rp_w, const float* __restrict__ rp_b,
    float* __restrict__ q) {
  int j = blockIdx.x * 256 + threadIdx.x;
  int bg = blockIdx.y * 8;
  float acc[8] = {0,0,0,0,0,0,0,0};
  for (int d = 0; d < D_; d++) {
    float w = rp_w[(size_t)d*D_ + j];
    #pragma unroll
    for (int i = 0; i < 8; i++) acc[i] += qv[(size_t)(bg+i)*D_ + d] * w;
  }
  float bias = rp_b[j];
  #pragma unroll
  for (int i = 0; i < 8; i++) q[(size_t)(bg+i)*D_ + j] = acc[i] + bias;
}

// ---------------- attention over 16 slots -> ctx_mem
__global__ __launch_bounds__(256) void k_attn(
    const float* __restrict__ mem, const float* __restrict__ q,
    float* __restrict__ cm) {
  int b = blockIdx.x, tid = threadIdx.x;
  __shared__ float attnw[S_];
  const float* mb = mem + (size_t)b*S_*D_;
  const float* qb = q + (size_t)b*D_;
  int s = tid >> 4, l = tid & 15;
  float p = 0.f;
  for (int d = l; d < D_; d += 16) p += mb[(size_t)s*D_ + d] * qb[d];
  p += __shfl_down(p, 8, 16);
  p += __shfl_down(p, 4, 16);
  p += __shfl_down(p, 2, 16);
  p += __shfl_down(p, 1, 16);
  if (l == 0) attnw[s] = p;
  __syncthreads();
  if (tid == 0) {
    float mx = attnw[0];
    for (int i = 1; i < S_; i++) mx = fmaxf(mx, attnw[i]);
    float se = 0.f, e[S_];
    for (int i = 0; i < S_; i++) { e[i] = expf(attnw[i] - mx); se += e[i]; }
    for (int i = 0; i < S_; i++) attnw[i] = e[i] / se;
  }
  __syncthreads();
  int d = tid * 4;
  float4 o = {0.f, 0.f, 0.f, 0.f};
  for (int si = 0; si < S_; si++) {
    float a = attnw[si];
    float4 mv = *(const float4*)&mb[(size_t)si*D_ + d];
    o.x += a*mv.x; o.y += a*mv.y; o.z += a*mv.z; o.w += a*mv.w;
  }
  *(float4*)&cm[(size_t)b*D_ + d] = o;
}

// ---------------- pack X64 = [qv(32); cm(32)] as bf16 [64][D]
__global__ __launch_bounds__(256) void k_xpack(
    const float* __restrict__ qv, const float* __restrict__ cm,
    unsigned short* __restrict__ x64) {
  int r = blockIdx.x;
  const float* src = (r < 32) ? (qv + (size_t)r*D_) : (cm + (size_t)(r-32)*D_);
  int d = threadIdx.x * 4;
  float4 v = *(const float4*)(src + d);
  us4 hv = {f2bf(v.x), f2bf(v.y), f2bf(v.z), f2bf(v.w)};
  *(us4*)(x64 + (size_t)r*D_ + d) = hv;
}

// ---------------- logits via MFMA: C[64][V] = X64 @ out_w (+out_b fused)
// rows 0..31 -> dl, rows 32..63 -> cl. out_w converted fp32->bf16 inline in LDS.
__global__ __launch_bounds__(256) void k_logits(
    const unsigned short* __restrict__ x64, const float* __restrict__ out_w,
    const float* __restrict__ out_b,
    float* __restrict__ dl, float* __restrict__ cl) {
  __shared__ unsigned short Bs[32*256];
  int n0 = blockIdx.x * 256;
  int tid = threadIdx.x;
  int lane = tid & 63, wave = tid >> 6;
  int wn = wave * 64;
  int fr = lane & 15, fq = lane >> 4;

  // thread 'tid' stages column n0+tid for all 32 k-rows of the tile
  bool colok = (n0 + tid) < V_;
  const float* gcol = out_w + (size_t)0*V_ + n0 + tid;

  f32x4 acc[4][4];
  #pragma unroll
  for (int i=0;i<4;i++)
    #pragma unroll
    for (int j=0;j<4;j++) acc[i][j] = (f32x4){0.f,0.f,0.f,0.f};

  for (int k0 = 0; k0 < D_; k0 += 32) {
    // stage: 32 rows x 256 cols fp32 -> bf16 LDS [k][n]
    #pragma unroll
    for (int k = 0; k < 32; k++) {
      float v = colok ? gcol[(size_t)(k0+k)*V_] : 0.f;
      Bs[k*256 + tid] = f2bf(v);
    }
    __syncthreads();

    // a-frags straight from global (X64 is 128KB, L2-hot)
    bf16x8 af[4], bf[4];
    #pragma unroll
    for (int i=0;i<4;i++)
      af[i] = *(const bf16x8*)(x64 + (size_t)(i*16+fr)*D_ + k0 + fq*8);
    #pragma unroll
    for (int j=0;j<4;j++) {
      int col = wn + j*16 + fr;
      unsigned short tmp[8];
      #pragma unroll
      for (int r8=0;r8<8;r8++) tmp[r8] = Bs[(fq*8+r8)*256 + col];
      bf[j] = *(const bf16x8*)tmp;
    }
    #pragma unroll
    for (int i=0;i<4;i++)
      #pragma unroll
      for (int j=0;j<4;j++)
        acc[i][j] = mfma_bf16(af[i], bf[j], acc[i][j]);
    __syncthreads();
  }

  #pragma unroll
  for (int j=0;j<4;j++) {
    int n = n0 + wn + j*16 + fr;
    if (n < V_) {
      float ob = out_b[n];
      #pragma unroll
      for (int i=0;i<4;i++) {
        #pragma unroll
        for (int r=0;r<4;r++) {
          int row = i*16 + fq*4 + r;
          float val = acc[i][j][r] + ob;
          if (row < 32) dl[(size_t)row*V_ + n] = val;
          else          cl[(size_t)(row-32)*V_ + n] = val;
        }
      }
    }
  }
}

// ---------------- conf = max softmax(dl) ; use_mem = conf < 0.8
__global__ __launch_bounds__(256) void k_conf(const float* __restrict__ dl, float* __restrict__ um) {
  int b = blockIdx.x, tid = threadIdx.x;
  __shared__ float red[4];
  const float* row = dl + (size_t)b*V_;
  float mx = -3.4e38f;
  for (int v = tid; v < V_; v += 256) mx = fmaxf(mx, row[v]);
  for (int off = 32; off > 0; off >>= 1) mx = fmaxf(mx, __shfl_down(mx, off, 64));
  if ((tid & 63) == 0) red[tid>>6] = mx;
  __syncthreads();
  mx = fmaxf(fmaxf(red[0], red[1]), fmaxf(red[2], red[3]));
  __syncthreads();
  float s = 0.f;
  for (int v = tid; v < V_; v += 256) s += expf(row[v] - mx);
  for (int off = 32; off > 0; off >>= 1) s += __shfl_down(s, off, 64);
  if ((tid & 63) == 0) red[tid>>6] = s;
  __syncthreads();
  if (tid == 0) {
    s = red[0]+red[1]+red[2]+red[3];
    float conf = 1.0f / s;
    um[b] = (conf < 0.8f) ? 1.0f : 0.0f;
  }
}

// ---------------- final select (um in {0,1} makes the mix an exact select)
__global__ __launch_bounds__(256) void k_out(
    const float* __restrict__ dl, const float* __restrict__ cl,
    const float* __restrict__ um, float* __restrict__ out) {
  int i = blockIdx.x*256 + threadIdx.x;
  if (i >= B_*V_) return;
  int b = i / V_;
  out[i] = (um[b] > 0.5f) ? cl[i] : dl[i];
}

extern "C" void kernel_launch(void* const* d_in, const int* in_sizes, int n_in,
                              void* d_out, int out_size, void* d_ws, size_t ws_size,
                              hipStream_t stream) {
  const int*   seq    = (const int*)d_in[0];
  const float* embed  = (const float*)d_in[1];
  const float* ff_w1  = (const float*)d_in[2];
  const float* ff_b1  = (const float*)d_in[3];
  const float* ff_w2  = (const float*)d_in[4];
  const float* ff_b2  = (const float*)d_in[5];
  const float* ln_g   = (const float*)d_in[6];
  const float* ln_b   = (const float*)d_in[7];
  const float* wg_w   = (const float*)d_in[8];
  const float* wg_b   = (const float*)d_in[9];
  const float* rp_w   = (const float*)d_in[10];
  const float* rp_b   = (const float*)d_in[11];
  const float* out_w  = (const float*)d_in[12];
  const float* out_b  = (const float*)d_in[13];
  const float* memory = (const float*)d_in[14];
  float* out = (float*)d_out;

  char* p = (char*)d_ws;
  auto alloc = [&](size_t bytes) { char* r = p; p += (bytes + 255) & ~(size_t)255; return r; };

  unsigned short* w1thi = (unsigned short*)alloc((size_t)H_*D_*2);
  unsigned short* w1tlo = (unsigned short*)alloc((size_t)H_*D_*2);
  unsigned short* w2thi = (unsigned short*)alloc((size_t)D_*H_*2);
  unsigned short* rhi   = (unsigned short*)alloc((size_t)M_*H_*2);
  // ehi/elo used only before gemm2; xbuf written only by gemm2 epilogue -> alias
  unsigned short* ehi   = (unsigned short*)alloc((size_t)M_*D_*2);
  unsigned short* elo   = (unsigned short*)alloc((size_t)M_*D_*2);
  float* xbuf  = (float*)ehi;   // M_*D_*4 bytes == ehi+elo region
  float* gu    = (float*)alloc((size_t)D_*4);
  float* scal  = (float*)alloc(256);
  float* w2gu  = (float*)alloc((size_t)H_*4);
  float* w2s   = (float*)alloc((size_t)H_*4);
  float* es    = (float*)alloc((size_t)M_*4);
  float* egu   = (float*)alloc((size_t)M_*4);
  float* rg    = (float*)alloc((size_t)M_*4);
  float* rsum  = (float*)alloc((size_t)M_*4);
  float* meanv = (float*)alloc((size_t)M_*4);
  float* rstdv = (float*)alloc((size_t)M_*4);
  float* slotv = (float*)alloc((size_t)M_*4);
  int*   sel   = (int*)alloc((size_t)B_*8*4);
  float* memb  = (float*)alloc((size_t)B_*S_*D_*4);
  float* qv    = (float*)alloc((size_t)B_*D_*4);
  float* qproj = (float*)alloc((size_t)B_*D_*4);
  float* cm    = (float*)alloc((size_t)B_*D_*4);
  unsigned short* x64 = (unsigned short*)alloc((size_t)64*D_*2);
  float* dl    = (float*)alloc((size_t)B_*V_*4);
  float* cl    = (float*)alloc((size_t)B_*V_*4);
  float* um    = (float*)alloc((size_t)B_*4);

  hipMemsetAsync(rg,   0, (size_t)M_*4, stream);
  hipMemsetAsync(rsum, 0, (size_t)M_*4, stream);
  hipLaunchKernelGGL(k_prep, dim3(1), dim3(256), 0, stream, wg_w, wg_b, ln_g, ln_b, ff_b2, gu, scal);
  hipLaunchKernelGGL(k_prep2, dim3(H_/4), dim3(256), 0, stream, ff_w2, gu, w2gu, w2s);
  hipLaunchKernelGGL(k_gsplit, dim3(M_), dim3(256), 0, stream, seq, embed, gu, ehi, elo, es, egu);
  hipLaunchKernelGGL(k_tsplit, dim3(D_/32, H_/32), dim3(256), 0, stream, ff_w1, w1thi, w1tlo, D_, H_);
  hipLaunchKernelGGL(k_tsplit, dim3(H_/32, D_/32), dim3(256), 0, stream, ff_w2, w2thi, (unsigned short*)nullptr, H_, D_);
  hipLaunchKernelGGL(k_gemm1, dim3(M_/128, H_/128), dim3(256), 0, stream,
                     ehi, elo, w1thi, w1tlo, ff_b1, w2gu, w2s, rhi, rg, rsum);
  hipLaunchKernelGGL(k_gemm2, dim3(M_/128, D_/128), dim3(256), 0, stream,
                     rhi, w2thi, ff_b2, seq, embed, xbuf);
  hipLaunchKernelGGL(k_stats, dim3(M_), dim3(256), 0, stream, xbuf, scal, es, egu, rg, rsum,
                     meanv, rstdv, slotv);
  hipLaunchKernelGGL(k_select, dim3(B_), dim3(256), 0, stream, slotv, sel);
  hipLaunchKernelGGL(k_buildmem, dim3(17, B_), dim3(256), 0, stream,
                     xbuf, meanv, rstdv, ln_g, ln_b, memory, sel, memb, qv);
  hipLaunchKernelGGL(k_qproj, dim3(D_/256, 4), dim3(256), 0, stream, qv, rp_w, rp_b, qproj);
  hipLaunchKernelGGL(k_attn, dim3(B_), dim3(256), 0, stream, memb, qproj, cm);
  hipLaunchKernelGGL(k_xpack, dim3(64), dim3(256), 0, stream, qv, cm, x64);
  hipLaunchKernelGGL(k_logits, dim3((V_+255)/256), dim3(256), 0, stream,
                     x64, out_w, out_b, dl, cl);
  hipLaunchKernelGGL(k_conf, dim3(B_), dim3(256), 0, stream, dl, um);
  hipLaunchKernelGGL(k_out, dim3((B_*V_+255)/256), dim3(256), 0, stream, dl, cl, um, out);
}

// Round 5
// 1066.679 us; speedup vs baseline: 1.1122x; 1.1122x over previous
//
#include <hip/hip_runtime.h>
#include <stdint.h>
#include <math.h>

#define B_ 32
#define T_ 512
#define D_ 1024
#define H_ 2048
#define V_ 50257
#define S_ 16
#define M_ (B_*T_)
#define TW_ 511

typedef __attribute__((ext_vector_type(8))) short bf16x8;
typedef __attribute__((ext_vector_type(4))) float f32x4;
typedef __attribute__((ext_vector_type(8))) unsigned short us8;
typedef __attribute__((ext_vector_type(4))) unsigned short us4;

__device__ inline unsigned short f2bf(float f) {
  uint32_t u = __builtin_bit_cast(uint32_t, f);
  uint32_t r = (u + 0x7FFFu + ((u >> 16) & 1u)) >> 16;
  return (unsigned short)r;
}
__device__ inline float bf2f(unsigned short h) {
  uint32_t u = ((uint32_t)h) << 16;
  return __builtin_bit_cast(float, u);
}

__device__ inline f32x4 mfma_bf16(bf16x8 a, bf16x8 b, f32x4 c) {
  return __builtin_amdgcn_mfma_f32_16x16x32_bf16(a, b, c, 0, 0, 0);
}

// async 16B global->LDS; LDS dest = wave-uniform base + lane*16
__device__ inline void gl2lds(const unsigned short* g, unsigned short* l) {
  __builtin_amdgcn_global_load_lds(
      (const __attribute__((address_space(1))) unsigned int*)g,
      (__attribute__((address_space(3))) unsigned int*)l,
      16, 0, 0);
}

// ---------------- prep: gu[d]=ln_g[d]*mean_s(wg_w[d,s]); scal: [0]=sum(gu),
// [1]=dot(ln_b,u)+mean(wg_b), [2]=b2.gu, [3]=sum(b2)
__global__ __launch_bounds__(256) void k_prep(
    const float* __restrict__ wg_w, const float* __restrict__ wg_b,
    const float* __restrict__ ln_g, const float* __restrict__ ln_b,
    const float* __restrict__ b2,
    float* __restrict__ gu, float* __restrict__ scal) {
  __shared__ float r1[4], r2[4], r3[4], r4[4];
  int tid = threadIdx.x;
  float psgu = 0.f, plbu = 0.f, pb2g = 0.f, pb2s = 0.f;
  for (int d = tid; d < D_; d += 256) {
    float s = 0.f;
    #pragma unroll
    for (int j = 0; j < S_; j++) s += wg_w[d*S_ + j];
    float uu = s * (1.0f/S_);
    float g = ln_g[d] * uu;
    gu[d] = g;
    psgu += g;
    plbu += ln_b[d] * uu;
    pb2g += b2[d] * g;
    pb2s += b2[d];
  }
  for (int off = 32; off > 0; off >>= 1) {
    psgu += __shfl_down(psgu, off, 64); plbu += __shfl_down(plbu, off, 64);
    pb2g += __shfl_down(pb2g, off, 64); pb2s += __shfl_down(pb2s, off, 64);
  }
  if ((tid & 63) == 0) { int w = tid>>6; r1[w]=psgu; r2[w]=plbu; r3[w]=pb2g; r4[w]=pb2s; }
  __syncthreads();
  if (tid == 0) {
    float sgu = r1[0]+r1[1]+r1[2]+r1[3];
    float lbu = r2[0]+r2[1]+r2[2]+r2[3];
    float ub = 0.f;
    for (int j = 0; j < S_; j++) ub += wg_b[j];
    scal[0] = sgu;
    scal[1] = lbu + ub * (1.0f/S_);
    scal[2] = r3[0]+r3[1]+r3[2]+r3[3];
    scal[3] = r4[0]+r4[1]+r4[2]+r4[3];
  }
}

// ---------------- prep2: w2gu[h] = W2[h,:].gu ; w2s[h] = sum_d W2[h,d]
__global__ __launch_bounds__(256) void k_prep2(
    const float* __restrict__ W2, const float* __restrict__ gu,
    float* __restrict__ w2gu, float* __restrict__ w2s) {
  int h = blockIdx.x*4 + (threadIdx.x >> 6);
  int lane = threadIdx.x & 63;
  const float4* row = (const float4*)(W2 + (size_t)h*D_);
  const float4* g4 = (const float4*)gu;
  float sg = 0.f, ss = 0.f;
  #pragma unroll
  for (int k = 0; k < 4; k++) {
    float4 w = row[lane + k*64];
    float4 g = g4[lane + k*64];
    sg += w.x*g.x + w.y*g.y + w.z*g.z + w.w*g.w;
    ss += w.x + w.y + w.z + w.w;
  }
  for (int off = 32; off > 0; off >>= 1) { sg += __shfl_down(sg, off, 64); ss += __shfl_down(ss, off, 64); }
  if (lane == 0) { w2gu[h] = sg; w2s[h] = ss; }
}

// ---------------- gather embed + hi/lo split + exact per-token e.gu / sum(e)
__global__ __launch_bounds__(256) void k_gsplit(
    const int* __restrict__ seq, const float* __restrict__ embed,
    const float* __restrict__ gu,
    unsigned short* __restrict__ ehi, unsigned short* __restrict__ elo,
    float* __restrict__ es, float* __restrict__ egu) {
  int m = blockIdx.x;
  int tok = seq[m];
  int tid = threadIdx.x;
  int d = tid * 4;
  float4 v = *(const float4*)(embed + (size_t)tok*D_ + d);
  float4 g = *(const float4*)(gu + d);
  unsigned short h0=f2bf(v.x), h1=f2bf(v.y), h2=f2bf(v.z), h3=f2bf(v.w);
  us4 hv = {h0,h1,h2,h3};
  us4 lv = {f2bf(v.x-bf2f(h0)), f2bf(v.y-bf2f(h1)), f2bf(v.z-bf2f(h2)), f2bf(v.w-bf2f(h3))};
  *(us4*)(ehi + (size_t)m*D_ + d) = hv;
  *(us4*)(elo + (size_t)m*D_ + d) = lv;
  float pe = v.x + v.y + v.z + v.w;
  float pg = v.x*g.x + v.y*g.y + v.z*g.z + v.w*g.w;
  __shared__ float le[4], lg[4];
  for (int off = 32; off > 0; off >>= 1) { pe += __shfl_down(pe, off, 64); pg += __shfl_down(pg, off, 64); }
  if ((tid & 63) == 0) { le[tid>>6] = pe; lg[tid>>6] = pg; }
  __syncthreads();
  if (tid == 0) {
    es[m]  = le[0]+le[1]+le[2]+le[3];
    egu[m] = lg[0]+lg[1]+lg[2]+lg[3];
  }
}

// ---------------- transpose + hi/lo split:  W (K x N) -> Thi/Tlo (N x K) bf16
__global__ __launch_bounds__(256) void k_tsplit(
    const float* __restrict__ W, unsigned short* __restrict__ Thi,
    unsigned short* __restrict__ Tlo, int K, int N) {
  __shared__ float tile[32][33];
  int k0 = blockIdx.x * 32, n0 = blockIdx.y * 32;
  int tx = threadIdx.x & 31, ty = threadIdx.x >> 5;
  for (int i = ty; i < 32; i += 8)
    tile[i][tx] = W[(size_t)(k0+i)*N + n0 + tx];
  __syncthreads();
  for (int i = ty; i < 32; i += 8) {
    float v = tile[tx][i];
    unsigned short hi = f2bf(v);
    size_t o = (size_t)(n0+i)*K + k0 + tx;
    Thi[o] = hi;
    if (Tlo) Tlo[o] = f2bf(v - bf2f(hi));
  }
}

// ---------------- GEMM1: r = relu(e @ w1t + b1) -> rhi (bf16), 3-pass split.
// Epilogue also accumulates exact projections rg[m]=sum_h r*w2gu[h], rsum[m]=sum_h r*w2s[h].
__global__ __launch_bounds__(256) void k_gemm1(
    const unsigned short* __restrict__ ehi, const unsigned short* __restrict__ elo,
    const unsigned short* __restrict__ Bhi, const unsigned short* __restrict__ Blo,
    const float* __restrict__ b1,
    const float* __restrict__ w2gu, const float* __restrict__ w2s,
    unsigned short* __restrict__ rhi,
    float* __restrict__ rg, float* __restrict__ rsum) {
  __shared__ unsigned short Ah[128*32], Al[128*32], Bh[128*32], Bl[128*32];
  int m0 = blockIdx.x * 128, n0 = blockIdx.y * 128;
  int tid = threadIdx.x;
  int lane = tid & 63, wave = tid >> 6;
  int wm = (wave & 1) * 64, wn = (wave >> 1) * 64;
  int fr = lane & 15, fq = lane >> 4;
  int srow = lane >> 2;
  // stage-side XOR swizzle: LDS slot (R, c) holds global colblock c ^ ((R>>1)&3)
  int scol = ((lane & 3) ^ ((lane >> 3) & 3)) * 8;
  // read-side: global colblock fq of row R lives at slot fq ^ ((fr>>1)&3)
  int csw = (fq ^ ((fr >> 1) & 3)) * 8;

  f32x4 acc[4][4];
  #pragma unroll
  for (int i=0;i<4;i++)
    #pragma unroll
    for (int j=0;j<4;j++) acc[i][j] = (f32x4){0.f,0.f,0.f,0.f};

  const unsigned short *pAh[2], *pAl[2], *pBh[2], *pBl[2];
  unsigned short *lAh[2], *lAl[2], *lBh[2], *lBl[2];
  #pragma unroll
  for (int t = 0; t < 2; t++) {
    int rb = t*64 + wave*16;
    pAh[t] = ehi + (size_t)(m0 + rb + srow)*D_ + scol;
    pAl[t] = elo + (size_t)(m0 + rb + srow)*D_ + scol;
    pBh[t] = Bhi + (size_t)(n0 + rb + srow)*D_ + scol;
    pBl[t] = Blo + (size_t)(n0 + rb + srow)*D_ + scol;
    lAh[t] = &Ah[rb*32]; lAl[t] = &Al[rb*32];
    lBh[t] = &Bh[rb*32]; lBl[t] = &Bl[rb*32];
  }

  for (int k0 = 0; k0 < D_; k0 += 32) {
    #pragma unroll
    for (int t = 0; t < 2; t++) {
      gl2lds(pAh[t], lAh[t]); gl2lds(pAl[t], lAl[t]);
      gl2lds(pBh[t], lBh[t]); gl2lds(pBl[t], lBl[t]);
      pAh[t] += 32; pAl[t] += 32; pBh[t] += 32; pBl[t] += 32;
    }
    __syncthreads();

    bf16x8 ah[4], al[4], bh[4], bl[4];
    #pragma unroll
    for (int i=0;i<4;i++) {
      ah[i] = *(const bf16x8*)&Ah[(wm + i*16 + fr)*32 + csw];
      al[i] = *(const bf16x8*)&Al[(wm + i*16 + fr)*32 + csw];
      bh[i] = *(const bf16x8*)&Bh[(wn + i*16 + fr)*32 + csw];
      bl[i] = *(const bf16x8*)&Bl[(wn + i*16 + fr)*32 + csw];
    }
    #pragma unroll
    for (int i=0;i<4;i++)
      #pragma unroll
      for (int j=0;j<4;j++) {
        acc[i][j] = mfma_bf16(ah[i], bh[j], acc[i][j]);
        acc[i][j] = mfma_bf16(ah[i], bl[j], acc[i][j]);
        acc[i][j] = mfma_bf16(al[i], bh[j], acc[i][j]);
      }
    __syncthreads();
  }

  // epilogue: relu + bf16 store + exact fp32 projections (reduced over fr lanes)
  float biasj[4], wgj[4], wsj[4];
  int gcj[4];
  #pragma unroll
  for (int j=0;j<4;j++) {
    gcj[j] = n0 + wn + j*16 + fr;
    biasj[j] = b1[gcj[j]];
    wgj[j] = w2gu[gcj[j]];
    wsj[j] = w2s[gcj[j]];
  }
  #pragma unroll
  for (int i=0;i<4;i++) {
    #pragma unroll
    for (int r=0;r<4;r++) {
      int gr = m0 + wm + i*16 + fq*4 + r;
      float sg = 0.f, ss = 0.f;
      #pragma unroll
      for (int j=0;j<4;j++) {
        float v = acc[i][j][r] + biasj[j];
        v = fmaxf(v, 0.f);
        rhi[(size_t)gr*H_ + gcj[j]] = f2bf(v);
        sg += v * wgj[j];
        ss += v * wsj[j];
      }
      #pragma unroll
      for (int off = 8; off > 0; off >>= 1) {
        sg += __shfl_down(sg, off, 16);
        ss += __shfl_down(ss, off, 16);
      }
      if (fr == 0) {
        atomicAdd(&rg[gr], sg);
        atomicAdd(&rsum[gr], ss);
      }
    }
  }
}

// ---------------- GEMM2 (1-pass bf16): x = rhi @ w2t + b2 + gather(embed,seq)
__global__ __launch_bounds__(256) void k_gemm2(
    const unsigned short* __restrict__ Ahi, const unsigned short* __restrict__ Bhig,
    const float* __restrict__ b2, const int* __restrict__ seq,
    const float* __restrict__ embed, float* __restrict__ xout) {
  __shared__ unsigned short Ah[128*32], Bh[128*32];
  int m0 = blockIdx.x * 128, n0 = blockIdx.y * 128;
  int tid = threadIdx.x;
  int lane = tid & 63, wave = tid >> 6;
  int wm = (wave & 1) * 64, wn = (wave >> 1) * 64;
  int fr = lane & 15, fq = lane >> 4;
  int srow = lane >> 2;
  int scol = ((lane & 3) ^ ((lane >> 3) & 3)) * 8;
  int csw = (fq ^ ((fr >> 1) & 3)) * 8;

  f32x4 acc[4][4];
  #pragma unroll
  for (int i=0;i<4;i++)
    #pragma unroll
    for (int j=0;j<4;j++) acc[i][j] = (f32x4){0.f,0.f,0.f,0.f};

  const unsigned short *pA[2], *pB[2];
  unsigned short *lA[2], *lB[2];
  #pragma unroll
  for (int t = 0; t < 2; t++) {
    int rb = t*64 + wave*16;
    pA[t] = Ahi  + (size_t)(m0 + rb + srow)*H_ + scol;
    pB[t] = Bhig + (size_t)(n0 + rb + srow)*H_ + scol;
    lA[t] = &Ah[rb*32]; lB[t] = &Bh[rb*32];
  }

  for (int k0 = 0; k0 < H_; k0 += 32) {
    #pragma unroll
    for (int t = 0; t < 2; t++) {
      gl2lds(pA[t], lA[t]); gl2lds(pB[t], lB[t]);
      pA[t] += 32; pB[t] += 32;
    }
    __syncthreads();

    bf16x8 ah[4], bh[4];
    #pragma unroll
    for (int i=0;i<4;i++) {
      ah[i] = *(const bf16x8*)&Ah[(wm + i*16 + fr)*32 + csw];
      bh[i] = *(const bf16x8*)&Bh[(wn + i*16 + fr)*32 + csw];
    }
    #pragma unroll
    for (int i=0;i<4;i++)
      #pragma unroll
      for (int j=0;j<4;j++)
        acc[i][j] = mfma_bf16(ah[i], bh[j], acc[i][j]);
    __syncthreads();
  }

  #pragma unroll
  for (int j=0;j<4;j++) {
    int gc = n0 + wn + j*16 + fr;
    float bias = b2[gc];
    #pragma unroll
    for (int i=0;i<4;i++) {
      #pragma unroll
      for (int r=0;r<4;r++) {
        int gr = m0 + wm + i*16 + fq*4 + r;
        float h = embed[(size_t)seq[gr]*D_ + gc];
        xout[(size_t)gr*D_ + gc] = acc[i][j][r] + bias + h;
      }
    }
  }
}

// ---------------- per-token stats: sum(x^2) from x; mu/sg from exact projections
__global__ __launch_bounds__(256) void k_stats(
    const float* __restrict__ x, const float* __restrict__ scal,
    const float* __restrict__ es, const float* __restrict__ egu,
    const float* __restrict__ rg, const float* __restrict__ rsum,
    float* __restrict__ meanv, float* __restrict__ rstdv, float* __restrict__ slotv) {
  int m = blockIdx.x, tid = threadIdx.x;
  const float4* xr = (const float4*)(x + (size_t)m*D_);
  float4 v = xr[tid];
  float sq = v.x*v.x + v.y*v.y + v.z*v.z + v.w*v.w;
  __shared__ float lq[4];
  for (int off = 32; off > 0; off >>= 1) sq += __shfl_down(sq, off, 64);
  if ((tid & 63) == 0) lq[tid>>6] = sq;
  __syncthreads();
  if (tid == 0) {
    sq = lq[0]+lq[1]+lq[2]+lq[3];
    float mu = (es[m] + rsum[m] + scal[3]) * (1.0f/D_);
    float sg = egu[m] + rg[m] + scal[2];
    float var = sq * (1.0f/D_) - mu*mu;
    float rs = 1.0f / sqrtf(var + 1e-5f);
    meanv[m] = mu; rstdv[m] = rs;
    slotv[m] = rs * (sg - mu * scal[0]) + scal[1];
  }
}

// ---------------- top-k selection, parallel argmax (stable lowest-index ties)
__global__ __launch_bounds__(256) void k_select(const float* __restrict__ slotv, int* __restrict__ sel) {
  __shared__ float v[TW_];
  __shared__ float bvs[4]; __shared__ int bis[4];
  int b = blockIdx.x, tid = threadIdx.x;
  for (int t = tid; t < TW_; t += 256) v[t] = slotv[(size_t)b*T_ + t];
  __syncthreads();
  for (int k = 0; k < 4; k++) {
    float bv = -3.4e38f; int bi = 0x7fffffff;
    for (int t = tid; t < TW_; t += 256) {
      float x = v[t];
      if (x > bv) { bv = x; bi = t; }
    }
    for (int off = 32; off > 0; off >>= 1) {
      float ov = __shfl_down(bv, off, 64); int oi = __shfl_down(bi, off, 64);
      if (ov > bv || (ov == bv && oi < bi)) { bv = ov; bi = oi; }
    }
    if ((tid & 63) == 0) { bvs[tid>>6] = bv; bis[tid>>6] = bi; }
    __syncthreads();
    if (tid == 0) {
      float fbv = bvs[0]; int fbi = bis[0];
      for (int w = 1; w < 4; w++)
        if (bvs[w] > fbv || (bvs[w] == fbv && bis[w] < fbi)) { fbv = bvs[w]; fbi = bis[w]; }
      sel[b*8 + k] = fbi; v[fbi] = -3.4e38f;
    }
    __syncthreads();
  }
  if (tid == 0) {
    for (int k = 4; k < 6; k++) {          // rev top-2 among first 8, excluding fwd picks
      float best = -3.4e38f; int bi = 0;
      for (int t = 0; t < 8; t++) if (v[t] > best) { best = v[t]; bi = t; }
      sel[b*8 + k] = bi; v[bi] = -3.4e38f;
    }
  }
}

// ---------------- build mem slots (0..5 selected hiddens, 6..15 memory) + query row
__global__ __launch_bounds__(256) void k_buildmem(
    const float* __restrict__ x, const float* __restrict__ meanv, const float* __restrict__ rstdv,
    const float* __restrict__ ln_g, const float* __restrict__ ln_b,
    const float* __restrict__ memory, const int* __restrict__ sel,
    float* __restrict__ mem, float* __restrict__ qv) {
  int s = blockIdx.x, b = blockIdx.y, tid = threadIdx.x;
  int d = tid * 4;
  if (s >= 6 && s < 16) {
    *(float4*)&mem[((size_t)b*S_ + s)*D_ + d] = *(const float4*)&memory[(size_t)s*D_ + d];
    return;
  }
  int t = (s == 16) ? (T_ - 1) : sel[b*8 + s];
  int m = b*T_ + t;
  float mu = meanv[m], rs = rstdv[m];
  float4 xv = *(const float4*)&x[(size_t)m*D_ + d];
  float4 g  = *(const float4*)&ln_g[d];
  float4 lb = *(const float4*)&ln_b[d];
  float4 o;
  o.x = (xv.x - mu)*rs*g.x + lb.x;
  o.y = (xv.y - mu)*rs*g.y + lb.y;
  o.z = (xv.z - mu)*rs*g.z + lb.z;
  o.w = (xv.w - mu)*rs*g.w + lb.w;
  if (s == 16) *(float4*)&qv[(size_t)b*D_ + d] = o;
  else         *(float4*)&mem[((size_t)b*S_ + s)*D_ + d] = o;
}

// ---------------- q = query @ rp_w + rp_b
__global__ __launch_bounds__(256) void k_qproj(
    const float* __restrict__ qv, const float* __restrict__ rp_w, const float* __restrict__ rp_b,
    float* __restrict__ q) {
  int j = blockIdx.x * 256 + threadIdx.x;
  int bg = blockIdx.y * 8;
  float acc[8] = {0,0,0,0,0,0,0,0};
  for (int d = 0; d < D_; d++) {
    float w = rp_w[(size_t)d*D_ + j];
    #pragma unroll
    for (int i = 0; i < 8; i++) acc[i] += qv[(size_t)(bg+i)*D_ + d] * w;
  }
  float bias = rp_b[j];
  #pragma unroll
  for (int i = 0; i < 8; i++) q[(size_t)(bg+i)*D_ + j] = acc[i] + bias;
}

// ---------------- attention over 16 slots -> ctx_mem
__global__ __launch_bounds__(256) void k_attn(
    const float* __restrict__ mem, const float* __restrict__ q,
    float* __restrict__ cm) {
  int b = blockIdx.x, tid = threadIdx.x;
  __shared__ float attnw[S_];
  const float* mb = mem + (size_t)b*S_*D_;
  const float* qb = q + (size_t)b*D_;
  int s = tid >> 4, l = tid & 15;
  float p = 0.f;
  for (int d = l; d < D_; d += 16) p += mb[(size_t)s*D_ + d] * qb[d];
  p += __shfl_down(p, 8, 16);
  p += __shfl_down(p, 4, 16);
  p += __shfl_down(p, 2, 16);
  p += __shfl_down(p, 1, 16);
  if (l == 0) attnw[s] = p;
  __syncthreads();
  if (tid == 0) {
    float mx = attnw[0];
    for (int i = 1; i < S_; i++) mx = fmaxf(mx, attnw[i]);
    float se = 0.f, e[S_];
    for (int i = 0; i < S_; i++) { e[i] = expf(attnw[i] - mx); se += e[i]; }
    for (int i = 0; i < S_; i++) attnw[i] = e[i] / se;
  }
  __syncthreads();
  int d = tid * 4;
  float4 o = {0.f, 0.f, 0.f, 0.f};
  for (int si = 0; si < S_; si++) {
    float a = attnw[si];
    float4 mv = *(const float4*)&mb[(size_t)si*D_ + d];
    o.x += a*mv.x; o.y += a*mv.y; o.z += a*mv.z; o.w += a*mv.w;
  }
  *(float4*)&cm[(size_t)b*D_ + d] = o;
}

// ---------------- pack X64 = [qv(32); cm(32)] as bf16 [64][D]
__global__ __launch_bounds__(256) void k_xpack(
    const float* __restrict__ qv, const float* __restrict__ cm,
    unsigned short* __restrict__ x64) {
  int r = blockIdx.x;
  const float* src = (r < 32) ? (qv + (size_t)r*D_) : (cm + (size_t)(r-32)*D_);
  int d = threadIdx.x * 4;
  float4 v = *(const float4*)(src + d);
  us4 hv = {f2bf(v.x), f2bf(v.y), f2bf(v.z), f2bf(v.w)};
  *(us4*)(x64 + (size_t)r*D_ + d) = hv;
}

// ---------------- logits via MFMA, D split in 4 chunks (grid.y), atomicAdd combine.
// C[64][V] = X64 @ out_w (+out_b in chunk 0). rows 0..31 -> dl, 32..63 -> cl.
__global__ __launch_bounds__(256) void k_logits(
    const unsigned short* __restrict__ x64, const float* __restrict__ out_w,
    const float* __restrict__ out_b,
    float* __restrict__ dl, float* __restrict__ cl) {
  __shared__ unsigned short Bs[32*256];
  int n0 = blockIdx.x * 256;
  int dc = blockIdx.y;
  int d0 = dc * (D_/4);
  int tid = threadIdx.x;
  int lane = tid & 63, wave = tid >> 6;
  int wn = wave * 64;
  int fr = lane & 15, fq = lane >> 4;

  bool colok = (n0 + tid) < V_;
  const float* gcol = out_w + (size_t)d0*V_ + n0 + tid;

  f32x4 acc[4][4];
  #pragma unroll
  for (int i=0;i<4;i++)
    #pragma unroll
    for (int j=0;j<4;j++) acc[i][j] = (f32x4){0.f,0.f,0.f,0.f};

  for (int k0 = 0; k0 < D_/4; k0 += 32) {
    // batch 32 independent loads into registers (keeps them all in flight),
    // then convert + ds_write
    float vv[32];
    #pragma unroll
    for (int k = 0; k < 32; k++)
      vv[k] = colok ? gcol[(size_t)(k0+k)*V_] : 0.f;
    #pragma unroll
    for (int k = 0; k < 32; k++)
      Bs[k*256 + tid] = f2bf(vv[k]);
    __syncthreads();

    // a-frags straight from global (X64 is 128KB, L2-hot)
    bf16x8 af[4], bfr[4];
    #pragma unroll
    for (int i=0;i<4;i++)
      af[i] = *(const bf16x8*)(x64 + (size_t)(i*16+fr)*D_ + d0 + k0 + fq*8);
    #pragma unroll
    for (int j=0;j<4;j++) {
      int col = wn + j*16 + fr;
      unsigned short tmp[8];
      #pragma unroll
      for (int r8=0;r8<8;r8++) tmp[r8] = Bs[(fq*8+r8)*256 + col];
      bfr[j] = *(const bf16x8*)tmp;
    }
    #pragma unroll
    for (int i=0;i<4;i++)
      #pragma unroll
      for (int j=0;j<4;j++)
        acc[i][j] = mfma_bf16(af[i], bfr[j], acc[i][j]);
    __syncthreads();
  }

  #pragma unroll
  for (int j=0;j<4;j++) {
    int n = n0 + wn + j*16 + fr;
    if (n < V_) {
      float ob = (dc == 0) ? out_b[n] : 0.f;
      #pragma unroll
      for (int i=0;i<4;i++) {
        #pragma unroll
        for (int r=0;r<4;r++) {
          int row = i*16 + fq*4 + r;
          float val = acc[i][j][r] + ob;
          if (row < 32) atomicAdd(&dl[(size_t)row*V_ + n], val);
          else          atomicAdd(&cl[(size_t)(row-32)*V_ + n], val);
        }
      }
    }
  }
}

// ---------------- conf = max softmax(dl) ; use_mem = conf < 0.8
__global__ __launch_bounds__(256) void k_conf(const float* __restrict__ dl, float* __restrict__ um) {
  int b = blockIdx.x, tid = threadIdx.x;
  __shared__ float red[4];
  const float* row = dl + (size_t)b*V_;
  float mx = -3.4e38f;
  for (int v = tid; v < V_; v += 256) mx = fmaxf(mx, row[v]);
  for (int off = 32; off > 0; off >>= 1) mx = fmaxf(mx, __shfl_down(mx, off, 64));
  if ((tid & 63) == 0) red[tid>>6] = mx;
  __syncthreads();
  mx = fmaxf(fmaxf(red[0], red[1]), fmaxf(red[2], red[3]));
  __syncthreads();
  float s = 0.f;
  for (int v = tid; v < V_; v += 256) s += expf(row[v] - mx);
  for (int off = 32; off > 0; off >>= 1) s += __shfl_down(s, off, 64);
  if ((tid & 63) == 0) red[tid>>6] = s;
  __syncthreads();
  if (tid == 0) {
    s = red[0]+red[1]+red[2]+red[3];
    float conf = 1.0f / s;
    um[b] = (conf < 0.8f) ? 1.0f : 0.0f;
  }
}

// ---------------- final select (um in {0,1} makes the mix an exact select)
__global__ __launch_bounds__(256) void k_out(
    const float* __restrict__ dl, const float* __restrict__ cl,
    const float* __restrict__ um, float* __restrict__ out) {
  int i = blockIdx.x*256 + threadIdx.x;
  if (i >= B_*V_) return;
  int b = i / V_;
  out[i] = (um[b] > 0.5f) ? cl[i] : dl[i];
}

extern "C" void kernel_launch(void* const* d_in, const int* in_sizes, int n_in,
                              void* d_out, int out_size, void* d_ws, size_t ws_size,
                              hipStream_t stream) {
  const int*   seq    = (const int*)d_in[0];
  const float* embed  = (const float*)d_in[1];
  const float* ff_w1  = (const float*)d_in[2];
  const float* ff_b1  = (const float*)d_in[3];
  const float* ff_w2  = (const float*)d_in[4];
  const float* ff_b2  = (const float*)d_in[5];
  const float* ln_g   = (const float*)d_in[6];
  const float* ln_b   = (const float*)d_in[7];
  const float* wg_w   = (const float*)d_in[8];
  const float* wg_b   = (const float*)d_in[9];
  const float* rp_w   = (const float*)d_in[10];
  const float* rp_b   = (const float*)d_in[11];
  const float* out_w  = (const float*)d_in[12];
  const float* out_b  = (const float*)d_in[13];
  const float* memory = (const float*)d_in[14];
  float* out = (float*)d_out;

  char* p = (char*)d_ws;
  auto alloc = [&](size_t bytes) { char* r = p; p += (bytes + 255) & ~(size_t)255; return r; };

  unsigned short* w1thi = (unsigned short*)alloc((size_t)H_*D_*2);
  unsigned short* w1tlo = (unsigned short*)alloc((size_t)H_*D_*2);
  unsigned short* w2thi = (unsigned short*)alloc((size_t)D_*H_*2);
  unsigned short* rhi   = (unsigned short*)alloc((size_t)M_*H_*2);
  // ehi/elo used only before gemm2; xbuf written only by gemm2 epilogue -> alias
  unsigned short* ehi   = (unsigned short*)alloc((size_t)M_*D_*2);
  unsigned short* elo   = (unsigned short*)alloc((size_t)M_*D_*2);
  float* xbuf  = (float*)ehi;   // M_*D_*4 bytes == ehi+elo region
  float* gu    = (float*)alloc((size_t)D_*4);
  float* scal  = (float*)alloc(256);
  float* w2gu  = (float*)alloc((size_t)H_*4);
  float* w2s   = (float*)alloc((size_t)H_*4);
  float* es    = (float*)alloc((size_t)M_*4);
  float* egu   = (float*)alloc((size_t)M_*4);
  float* rg    = (float*)alloc((size_t)M_*4);
  float* rsum  = (float*)alloc((size_t)M_*4);
  float* meanv = (float*)alloc((size_t)M_*4);
  float* rstdv = (float*)alloc((size_t)M_*4);
  float* slotv = (float*)alloc((size_t)M_*4);
  int*   sel   = (int*)alloc((size_t)B_*8*4);
  float* memb  = (float*)alloc((size_t)B_*S_*D_*4);
  float* qv    = (float*)alloc((size_t)B_*D_*4);
  float* qproj = (float*)alloc((size_t)B_*D_*4);
  float* cm    = (float*)alloc((size_t)B_*D_*4);
  unsigned short* x64 = (unsigned short*)alloc((size_t)64*D_*2);
  float* dl    = (float*)alloc((size_t)B_*V_*4);
  float* cl    = (float*)alloc((size_t)B_*V_*4);
  float* um    = (float*)alloc((size_t)B_*4);

  hipMemsetAsync(rg,   0, (size_t)M_*4, stream);
  hipMemsetAsync(rsum, 0, (size_t)M_*4, stream);
  hipMemsetAsync(dl,   0, (size_t)B_*V_*4, stream);
  hipMemsetAsync(cl,   0, (size_t)B_*V_*4, stream);
  hipLaunchKernelGGL(k_prep, dim3(1), dim3(256), 0, stream, wg_w, wg_b, ln_g, ln_b, ff_b2, gu, scal);
  hipLaunchKernelGGL(k_prep2, dim3(H_/4), dim3(256), 0, stream, ff_w2, gu, w2gu, w2s);
  hipLaunchKernelGGL(k_gsplit, dim3(M_), dim3(256), 0, stream, seq, embed, gu, ehi, elo, es, egu);
  hipLaunchKernelGGL(k_tsplit, dim3(D_/32, H_/32), dim3(256), 0, stream, ff_w1, w1thi, w1tlo, D_, H_);
  hipLaunchKernelGGL(k_tsplit, dim3(H_/32, D_/32), dim3(256), 0, stream, ff_w2, w2thi, (unsigned short*)nullptr, H_, D_);
  hipLaunchKernelGGL(k_gemm1, dim3(M_/128, H_/128), dim3(256), 0, stream,
                     ehi, elo, w1thi, w1tlo, ff_b1, w2gu, w2s, rhi, rg, rsum);
  hipLaunchKernelGGL(k_gemm2, dim3(M_/128, D_/128), dim3(256), 0, stream,
                     rhi, w2thi, ff_b2, seq, embed, xbuf);
  hipLaunchKernelGGL(k_stats, dim3(M_), dim3(256), 0, stream, xbuf, scal, es, egu, rg, rsum,
                     meanv, rstdv, slotv);
  hipLaunchKernelGGL(k_select, dim3(B_), dim3(256), 0, stream, slotv, sel);
  hipLaunchKernelGGL(k_buildmem, dim3(17, B_), dim3(256), 0, stream,
                     xbuf, meanv, rstdv, ln_g, ln_b, memory, sel, memb, qv);
  hipLaunchKernelGGL(k_qproj, dim3(D_/256, 4), dim3(256), 0, stream, qv, rp_w, rp_b, qproj);
  hipLaunchKernelGGL(k_attn, dim3(B_), dim3(256), 0, stream, memb, qproj, cm);
  hipLaunchKernelGGL(k_xpack, dim3(64), dim3(256), 0, stream, qv, cm, x64);
  hipLaunchKernelGGL(k_logits, dim3((V_+255)/256, 4), dim3(256), 0, stream,
                     x64, out_w, out_b, dl, cl);
  hipLaunchKernelGGL(k_conf, dim3(B_), dim3(256), 0, stream, dl, um);
  hipLaunchKernelGGL(k_out, dim3((B_*V_+255)/256), dim3(256), 0, stream, dl, cl, um, out);
}